// Round 6
// baseline (50.845 us; speedup 1.0000x reference)
//
#include <hip/hip_runtime.h>

// YOLO v1 loss on MI355X — round 6.
// One wave per block, one 64-cell tile per block: 15x global_load_lds_dwordx4
// (coalesced, zero VGPR cost) -> single vmcnt(0) -> 120-B-stride LDS gather ->
// per-cell math -> wave-reduced partials to ws. Latency hidden purely by TLP
// (10 single-wave blocks resident per CU). Tiny reduce kernel sums partials.
// bounding_boxes (8192,7,7,30) f32, ground_truth (8192,7,7,30) f32.
// Output: 6 float32 scalars.

#define CH 30
#define NCELLS (8192 * 49)        // 401408
#define TCELLS 64                 // cells per block-tile
#define TB (TCELLS * CH * 4)      // 7680 B per array per tile
#define NTILES (NCELLS / TCELLS)  // 6272 blocks

__device__ __forceinline__ float iou_one(const float* __restrict__ B,
                                         const float* __restrict__ G,
                                         float fx, float fy) {
    float px = truncf((B[0] + fx) * 64.0f);
    float py = truncf((B[1] + fy) * 64.0f);
    float pw = truncf(B[2] * 448.0f);
    float ph = truncf(B[3] * 448.0f);
    float x1 = fmaxf(0.0f, px - pw * 0.5f);
    float y1 = fmaxf(0.0f, py - ph * 0.5f);
    float x2 = fminf(447.0f, px + pw * 0.5f);
    float y2 = fminf(447.0f, py + ph * 0.5f);
    float parea = (x2 - x1) * (y2 - y1);
    float lx = fmaxf(x1, G[5]);
    float rx = fminf(x2, G[7]);
    float uy = fmaxf(y1, G[6]);
    float dy = fminf(y2, G[8]);
    float inter = (rx - lx) * (dy - uy);
    bool valid = (rx >= lx) && (dy >= uy);
    return valid ? inter / (parea + G[9] - inter) : 0.0f;
}

__global__ __launch_bounds__(64) void yolo_v1_loss_main(
    const float* __restrict__ bbf, const float* __restrict__ gtf,
    float* __restrict__ ws) {
    __shared__ char lds[2 * TB];  // 15360 B -> 10 blocks/CU

    const int lane = threadIdx.x;  // 0..63 (one wave)
    const int tile = blockIdx.x;   // 0..NTILES-1

    const char* bbt = (const char*)bbf + (size_t)tile * TB;
    const char* gtt = (const char*)gtf + (size_t)tile * TB;

    // ---- stage: 15 coalesced global_load_lds_dwordx4 (no VGPRs used) ----
    // LDS dest is wave-uniform base; HW adds lane*16. Global src is per-lane.
#pragma unroll
    for (int i = 0; i < 15; ++i) {
        int f = i * 1024 + lane * 16;
        const char* src = (f < TB) ? (bbt + f) : (gtt + (f - TB));
        __builtin_amdgcn_global_load_lds(
            (const __attribute__((address_space(1))) void*)src,
            (__attribute__((address_space(3))) void*)(lds + i * 1024), 16, 0,
            0);
    }

    // gll -> ds_read dependency is not tracked by the compiler: drain once.
    asm volatile("s_waitcnt vmcnt(0)" ::: "memory");

    // ---- LDS gather: lane l owns cell l (120-B stride, 15+15 ds_read_b64) ---
    float vb[CH], vg[CH];
    const float2* pb2 = (const float2*)(lds + lane * 120);
    const float2* pg2 = (const float2*)(lds + TB + lane * 120);
#pragma unroll
    for (int i = 0; i < 15; ++i) {
        *(float2*)(vb + 2 * i) = pb2[i];
        *(float2*)(vg + 2 * i) = pg2[i];
    }

    // ---- per-cell math ----
    int cell = tile * TCELLS + lane;
    int b = cell / 49;
    int rem = cell - b * 49;
    int gy = rem / 7;
    int gx = rem - gy * 7;
    float fx = (float)gx, fy = (float)gy;

    const float* B = vb;
    const float* G = vg;

    float iou1 = iou_one(B, G, fx, fy);
    float iou2 = iou_one(B + 5, G, fx, fy);
    bool r1 = iou1 > iou2;
    const float* P = r1 ? B : (B + 5);   // responsible box
    const float* Nb = r1 ? (B + 5) : B;  // other box
    float iou = r1 ? iou1 : iou2;

    float fm = (rintf(G[4]) != 0.0f) ? 1.0f : 0.0f;
    float noobj = 0.5f * (B[4] * B[4] + B[9] * B[9]);

    float dx = P[0] - G[0];
    float dyv = P[1] - G[1];
    float dw = sqrtf(P[2]) - sqrtf(G[2]);
    float dh = sqrtf(P[3]) - sqrtf(G[3]);
    float coord = 5.0f * (dx * dx + dyv * dyv + dw * dw + dh * dh);

    float dc = P[4] - iou;
    float conf = dc * dc + 0.5f * Nb[4] * Nb[4];

    float cls = 0.f;
#pragma unroll
    for (int k = 0; k < 20; ++k) {
        float d = G[10 + k] - B[10 + k];
        cls += d * d;
    }

    float ifm = 1.0f - fm;
    float a_loss = fm * (coord + conf + cls) + ifm * noobj;
    float a_coord = fm * coord;
    float a_conf = fm * conf + ifm * noobj;
    float a_cls = fm * cls;
    float a_iou = fm * iou;
    float a_obj = fm;

    // ---- wave reduce (64-wide), partials straight to workspace ----
#pragma unroll
    for (int off = 32; off > 0; off >>= 1) {
        a_loss += __shfl_down(a_loss, off);
        a_coord += __shfl_down(a_coord, off);
        a_conf += __shfl_down(a_conf, off);
        a_cls += __shfl_down(a_cls, off);
        a_iou += __shfl_down(a_iou, off);
        a_obj += __shfl_down(a_obj, off);
    }
    if (lane == 0) {
        ws[0 * NTILES + tile] = a_loss;
        ws[1 * NTILES + tile] = a_coord;
        ws[2 * NTILES + tile] = a_conf;
        ws[3 * NTILES + tile] = a_cls;
        ws[4 * NTILES + tile] = a_iou;
        ws[5 * NTILES + tile] = a_obj;
    }
}

// 6 waves; wave j reduces the NTILES partials of output j.
__global__ __launch_bounds__(384) void yolo_v1_loss_reduce(
    const float* __restrict__ ws, float* __restrict__ out) {
    const int tid = threadIdx.x;
    const int j = tid >> 6;
    const int lane = tid & 63;
    float s = 0.f;
    for (int i = lane; i < NTILES; i += 64) s += ws[j * NTILES + i];
#pragma unroll
    for (int off = 32; off > 0; off >>= 1) s += __shfl_down(s, off);
    if (lane == 0) out[j] = s;
}

extern "C" void kernel_launch(void* const* d_in, const int* in_sizes, int n_in,
                              void* d_out, int out_size, void* d_ws,
                              size_t ws_size, hipStream_t stream) {
    const float* bb = (const float*)d_in[0];
    const float* gt = (const float*)d_in[1];
    float* out = (float*)d_out;
    float* ws = (float*)d_ws;
    yolo_v1_loss_main<<<NTILES, 64, 0, stream>>>(bb, gt, ws);
    yolo_v1_loss_reduce<<<1, 384, 0, stream>>>(ws, out);
}

// Round 7
// 43.721 us; speedup vs baseline: 1.1629x; 1.1629x over previous
//
#include <hip/hip_runtime.h>

// YOLO v1 loss on MI355X — round 7.
// Back to the R3 winner (direct hoisted float4 loads, no LDS staging, no
// atomics), with 2x thread-level parallelism: ONE cell per thread via
// parity-split phases. Even cells: 240B-pair-aligned window OFF=0; odd cells:
// window starts 2 floats early, OFF=2. OFF is a template constant selected by
// a wave-uniform branch on blockIdx -> all register indexing static.
// bounding_boxes (8192,7,7,30) f32, ground_truth (8192,7,7,30) f32.
// Output: 6 float32 scalars.

#define CH 30
#define NCELLS (8192 * 49)       // 401408
#define BLK 256
#define NBLK (NCELLS / BLK)      // 1568 blocks
#define HBLK (NBLK / 2)          // 784: blocks [0,784) even cells, rest odd

__device__ __forceinline__ float iou_one(const float* __restrict__ B,
                                         const float* __restrict__ G,
                                         float fx, float fy) {
    float px = truncf((B[0] + fx) * 64.0f);
    float py = truncf((B[1] + fy) * 64.0f);
    float pw = truncf(B[2] * 448.0f);
    float ph = truncf(B[3] * 448.0f);
    float x1 = fmaxf(0.0f, px - pw * 0.5f);
    float y1 = fmaxf(0.0f, py - ph * 0.5f);
    float x2 = fminf(447.0f, px + pw * 0.5f);
    float y2 = fminf(447.0f, py + ph * 0.5f);
    float parea = (x2 - x1) * (y2 - y1);
    float lx = fmaxf(x1, G[5]);
    float rx = fminf(x2, G[7]);
    float uy = fmaxf(y1, G[6]);
    float dy = fminf(y2, G[8]);
    float inter = (rx - lx) * (dy - uy);
    bool valid = (rx >= lx) && (dy >= uy);
    return valid ? inter / (parea + G[9] - inter) : 0.0f;
}

// Process one cell. OFF (0 or 2) is compile-time so vb/vg indexing is static.
// f4idx: first float4 of the 8-float4 window covering this cell in each array.
template <int OFF>
__device__ __forceinline__ void do_cell(const float4* __restrict__ b4,
                                        const float4* __restrict__ g4,
                                        size_t f4idx, int cell, float acc[6]) {
    float vb[32], vg[32];
#pragma unroll
    for (int i = 0; i < 8; ++i) {
        *(float4*)(vb + 4 * i) = b4[f4idx + i];
        *(float4*)(vg + 4 * i) = g4[f4idx + i];
    }
    const float* B = vb + OFF;
    const float* G = vg + OFF;

    int rem = cell % 49;
    int gy = rem / 7;
    int gx = rem - gy * 7;
    float fx = (float)gx, fy = (float)gy;

    float iou1 = iou_one(B, G, fx, fy);
    float iou2 = iou_one(B + 5, G, fx, fy);
    bool r1 = iou1 > iou2;
    const float* P = r1 ? B : (B + 5);   // responsible box
    const float* Nb = r1 ? (B + 5) : B;  // other box
    float iou = r1 ? iou1 : iou2;

    float fm = (rintf(G[4]) != 0.0f) ? 1.0f : 0.0f;
    float noobj = 0.5f * (B[4] * B[4] + B[9] * B[9]);

    float dx = P[0] - G[0];
    float dyv = P[1] - G[1];
    float dw = sqrtf(P[2]) - sqrtf(G[2]);
    float dh = sqrtf(P[3]) - sqrtf(G[3]);
    float coord = 5.0f * (dx * dx + dyv * dyv + dw * dw + dh * dh);

    float dc = P[4] - iou;
    float conf = dc * dc + 0.5f * Nb[4] * Nb[4];

    float cls = 0.f;
#pragma unroll
    for (int k = 0; k < 20; ++k) {
        float d = G[10 + k] - B[10 + k];
        cls += d * d;
    }

    float ifm = 1.0f - fm;
    acc[0] += fm * (coord + conf + cls) + ifm * noobj;
    acc[1] += fm * coord;
    acc[2] += fm * conf + ifm * noobj;
    acc[3] += fm * cls;
    acc[4] += fm * iou;
    acc[5] += fm;
}

__global__ __launch_bounds__(256, 5) void yolo_v1_loss_main(
    const float* __restrict__ bbf, const float* __restrict__ gtf,
    float* __restrict__ ws) {
    __shared__ float sRed[4][6];

    const int tid = threadIdx.x;
    const int bid = blockIdx.x;
    const float4* b4 = (const float4*)bbf;
    const float4* g4 = (const float4*)gtf;

    float acc[6] = {0.f, 0.f, 0.f, 0.f, 0.f, 0.f};

    if (bid < HBLK) {
        // even cells: cell = 2u, window base f4 = 15u, cell floats at +0
        size_t u = (size_t)bid * BLK + tid;  // 0..200703
        do_cell<0>(b4, g4, 15 * u, (int)(2 * u), acc);
    } else {
        // odd cells: cell = 2u+1, floats [60u+30,60u+60) -> window f4 base
        // 15u+7 (covers floats 60u+28..60u+60), cell data at +2
        size_t u = (size_t)(bid - HBLK) * BLK + tid;
        do_cell<2>(b4, g4, 15 * u + 7, (int)(2 * u + 1), acc);
    }

    // ---- wave reduce (64-wide) ----
#pragma unroll
    for (int off = 32; off > 0; off >>= 1) {
#pragma unroll
        for (int j = 0; j < 6; ++j) acc[j] += __shfl_down(acc[j], off);
    }
    int wave = tid >> 6;
    int lane = tid & 63;
    if (lane == 0) {
#pragma unroll
        for (int j = 0; j < 6; ++j) sRed[wave][j] = acc[j];
    }
    __syncthreads();
    if (tid == 0) {
#pragma unroll
        for (int j = 0; j < 6; ++j) {
            ws[j * NBLK + bid] =
                sRed[0][j] + sRed[1][j] + sRed[2][j] + sRed[3][j];
        }
    }
}

// 768 threads = 12 waves; wave-pair (2 waves) per output j.
__global__ __launch_bounds__(768) void yolo_v1_loss_reduce(
    const float* __restrict__ ws, float* __restrict__ out) {
    __shared__ float sp[12];
    const int tid = threadIdx.x;
    const int j = tid >> 7;        // 0..5 (128 threads per output)
    const int sub = tid & 127;
    float s = 0.f;
    for (int i = sub; i < NBLK; i += 128) s += ws[j * NBLK + i];
#pragma unroll
    for (int off = 32; off > 0; off >>= 1) s += __shfl_down(s, off);
    const int wave = tid >> 6;
    if ((tid & 63) == 0) sp[wave] = s;
    __syncthreads();
    if (tid < 6) out[tid] = sp[2 * tid] + sp[2 * tid + 1];
}

extern "C" void kernel_launch(void* const* d_in, const int* in_sizes, int n_in,
                              void* d_out, int out_size, void* d_ws,
                              size_t ws_size, hipStream_t stream) {
    const float* bb = (const float*)d_in[0];
    const float* gt = (const float*)d_in[1];
    float* out = (float*)d_out;
    float* ws = (float*)d_ws;
    yolo_v1_loss_main<<<NBLK, BLK, 0, stream>>>(bb, gt, ws);
    yolo_v1_loss_reduce<<<1, 768, 0, stream>>>(ws, out);
}

// Round 8
// 43.371 us; speedup vs baseline: 1.1723x; 1.0081x over previous
//
#include <hip/hip_runtime.h>

// YOLO v1 loss on MI355X — round 8.
// Direct-load family (no LDS staging — 0-for-3 across R4/R5/R6). One cell per
// thread via PER-WAVE parity within a block: even-parity waves load float4
// window [15u, 15u+8) (floats 0..31 of pair u, cell 2u at +0); odd-parity
// waves load [15u+7, 15u+15) (floats 28..59, cell 2u+1 at +2) over the SAME
// pair range -> overlapping lines are co-resident on the same CU (L1/L2 hit),
// so HBM fetch stays ~1x (R7's split phases fetched 2x53 MB). Parity is
// wave-uniform -> template<OFF> keeps all register indexing static.
// 16 float4 loads/thread hoisted, ~95 VGPR, no LDS, ~20 waves/CU.
// bounding_boxes (8192,7,7,30) f32, ground_truth (8192,7,7,30) f32.
// Output: 6 float32 scalars.

#define NCELLS (8192 * 49)            // 401408
#define NPAIRS (NCELLS / 2)           // 200704
#define BLK 256
#define PPB 128                       // pairs per block (4 waves: 2 parities x 2)
#define NBLK (NPAIRS / PPB)           // 1568
#define NW (NBLK * 4)                 // 6272 wave partial-sets

__device__ __forceinline__ float iou_one(const float* __restrict__ B,
                                         const float* __restrict__ G,
                                         float fx, float fy) {
    float px = truncf((B[0] + fx) * 64.0f);
    float py = truncf((B[1] + fy) * 64.0f);
    float pw = truncf(B[2] * 448.0f);
    float ph = truncf(B[3] * 448.0f);
    float x1 = fmaxf(0.0f, px - pw * 0.5f);
    float y1 = fmaxf(0.0f, py - ph * 0.5f);
    float x2 = fminf(447.0f, px + pw * 0.5f);
    float y2 = fminf(447.0f, py + ph * 0.5f);
    float parea = (x2 - x1) * (y2 - y1);
    float lx = fmaxf(x1, G[5]);
    float rx = fminf(x2, G[7]);
    float uy = fmaxf(y1, G[6]);
    float dy = fminf(y2, G[8]);
    float inter = (rx - lx) * (dy - uy);
    bool valid = (rx >= lx) && (dy >= uy);
    return valid ? inter / (parea + G[9] - inter) : 0.0f;
}

// One cell. OFF is compile-time (0 = even cell, 2 = odd cell) so vb/vg
// indexing is static. f4idx: first float4 of the 8-float4 window.
template <int OFF>
__device__ __forceinline__ void do_cell(const float4* __restrict__ b4,
                                        const float4* __restrict__ g4,
                                        size_t f4idx, int cell, float acc[6]) {
    float vb[32], vg[32];
#pragma unroll
    for (int i = 0; i < 8; ++i) {
        *(float4*)(vb + 4 * i) = b4[f4idx + i];
        *(float4*)(vg + 4 * i) = g4[f4idx + i];
    }
    const float* B = vb + OFF;
    const float* G = vg + OFF;

    int rem = cell % 49;
    int gy = rem / 7;
    int gx = rem - gy * 7;
    float fx = (float)gx, fy = (float)gy;

    float iou1 = iou_one(B, G, fx, fy);
    float iou2 = iou_one(B + 5, G, fx, fy);
    bool r1 = iou1 > iou2;
    const float* P = r1 ? B : (B + 5);   // responsible box
    const float* Nb = r1 ? (B + 5) : B;  // other box
    float iou = r1 ? iou1 : iou2;

    float fm = (rintf(G[4]) != 0.0f) ? 1.0f : 0.0f;
    float noobj = 0.5f * (B[4] * B[4] + B[9] * B[9]);

    float dx = P[0] - G[0];
    float dyv = P[1] - G[1];
    float dw = sqrtf(P[2]) - sqrtf(G[2]);
    float dh = sqrtf(P[3]) - sqrtf(G[3]);
    float coord = 5.0f * (dx * dx + dyv * dyv + dw * dw + dh * dh);

    float dc = P[4] - iou;
    float conf = dc * dc + 0.5f * Nb[4] * Nb[4];

    float cls = 0.f;
#pragma unroll
    for (int k = 0; k < 20; ++k) {
        float d = G[10 + k] - B[10 + k];
        cls += d * d;
    }

    float ifm = 1.0f - fm;
    acc[0] += fm * (coord + conf + cls) + ifm * noobj;
    acc[1] += fm * coord;
    acc[2] += fm * conf + ifm * noobj;
    acc[3] += fm * cls;
    acc[4] += fm * iou;
    acc[5] += fm;
}

__global__ __launch_bounds__(256) void yolo_v1_loss_main(
    const float* __restrict__ bbf, const float* __restrict__ gtf,
    float* __restrict__ ws) {
    const int tid = threadIdx.x;
    const int lane = tid & 63;
    const int w = tid >> 6;            // 0..3
    const int parity = w & 1;          // wave-uniform
    // waves 0,1 -> pairs [base, base+64); waves 2,3 -> [base+64, base+128)
    const size_t pu = (size_t)blockIdx.x * PPB + (size_t)(w >> 1) * 64 + lane;
    const int gwave = blockIdx.x * 4 + w;

    const float4* b4 = (const float4*)bbf;
    const float4* g4 = (const float4*)gtf;

    float acc[6] = {0.f, 0.f, 0.f, 0.f, 0.f, 0.f};

    if (parity == 0) {
        // cell 2u: floats [60u, 60u+30) ⊂ f4 [15u, 15u+8), data at +0
        do_cell<0>(b4, g4, 15 * pu, (int)(2 * pu), acc);
    } else {
        // cell 2u+1: floats [60u+30, 60u+60) ⊂ f4 [15u+7, 15u+15), data at +2
        do_cell<2>(b4, g4, 15 * pu + 7, (int)(2 * pu + 1), acc);
    }

    // ---- wave reduce (64-wide), partials straight to workspace ----
#pragma unroll
    for (int off = 32; off > 0; off >>= 1) {
#pragma unroll
        for (int j = 0; j < 6; ++j) acc[j] += __shfl_down(acc[j], off);
    }
    if (lane == 0) {
#pragma unroll
        for (int j = 0; j < 6; ++j) ws[j * NW + gwave] = acc[j];
    }
}

// 768 threads = 12 waves; 128 threads (2 waves) per output j.
__global__ __launch_bounds__(768) void yolo_v1_loss_reduce(
    const float* __restrict__ ws, float* __restrict__ out) {
    __shared__ float sp[12];
    const int tid = threadIdx.x;
    const int j = tid >> 7;  // 0..5
    const int sub = tid & 127;
    float s = 0.f;
    for (int i = sub; i < NW; i += 128) s += ws[j * NW + i];
#pragma unroll
    for (int off = 32; off > 0; off >>= 1) s += __shfl_down(s, off);
    const int wave = tid >> 6;
    if ((tid & 63) == 0) sp[wave] = s;
    __syncthreads();
    if (tid < 6) out[tid] = sp[2 * tid] + sp[2 * tid + 1];
}

extern "C" void kernel_launch(void* const* d_in, const int* in_sizes, int n_in,
                              void* d_out, int out_size, void* d_ws,
                              size_t ws_size, hipStream_t stream) {
    const float* bb = (const float*)d_in[0];
    const float* gt = (const float*)d_in[1];
    float* out = (float*)d_out;
    float* ws = (float*)d_ws;
    yolo_v1_loss_main<<<NBLK, BLK, 0, stream>>>(bb, gt, ws);
    yolo_v1_loss_reduce<<<1, 768, 0, stream>>>(ws, out);
}

// Round 9
// 29.088 us; speedup vs baseline: 1.7480x; 1.4910x over previous
//
#include <hip/hip_runtime.h>

// YOLO v1 loss on MI355X — round 9.
// Wave-private DOUBLE-BUFFERED global_load_lds pipeline with COUNTED vmcnt
// (T3/T4): issue tile k+1's 15 coalesced gll into buf^1, s_waitcnt vmcnt(15)
// (= tile k's loads landed, FIFO), gather tile k from LDS, compute. vmcnt(0)
// only on the final tile. No barriers (wave-private buffers). 4 tiles/wave,
// 2 waves/block, 61440 B LDS -> 2 blocks/CU (HBM-bound by design).
// bounding_boxes (8192,7,7,30) f32, ground_truth (8192,7,7,30) f32.
// Output: 6 float32 scalars.

#define CH 30
#define NCELLS (8192 * 49)        // 401408
#define TCELLS 64                 // cells per tile
#define AB (TCELLS * CH * 4)      // 7680 B per array per tile
#define TB (2 * AB)               // 15360 B per tile (bb half + gt half)
#define NTILES (NCELLS / TCELLS)  // 6272
#define TPW 4                     // tiles per wave
#define NW (NTILES / TPW)         // 1568 waves
#define WPB 2
#define NBLOCKS (NW / WPB)        // 784

__device__ __forceinline__ void stage_tile(const char* __restrict__ bb,
                                           const char* __restrict__ gt,
                                           char* dst, int tile, int lane) {
    const char* bbt = bb + (size_t)tile * AB;
    const char* gtt = gt + (size_t)tile * AB;
#pragma unroll
    for (int i = 0; i < 15; ++i) {
        int f = i * 1024 + lane * 16;  // 0..15344
        const char* src = (f < AB) ? (bbt + f) : (gtt + (f - AB));
        __builtin_amdgcn_global_load_lds(
            (const __attribute__((address_space(1))) void*)src,
            (__attribute__((address_space(3))) void*)(dst + i * 1024), 16, 0,
            0);
    }
}

__device__ __forceinline__ float iou_one(const float* __restrict__ B,
                                         const float* __restrict__ G,
                                         float fx, float fy) {
    float px = truncf((B[0] + fx) * 64.0f);
    float py = truncf((B[1] + fy) * 64.0f);
    float pw = truncf(B[2] * 448.0f);
    float ph = truncf(B[3] * 448.0f);
    float x1 = fmaxf(0.0f, px - pw * 0.5f);
    float y1 = fmaxf(0.0f, py - ph * 0.5f);
    float x2 = fminf(447.0f, px + pw * 0.5f);
    float y2 = fminf(447.0f, py + ph * 0.5f);
    float parea = (x2 - x1) * (y2 - y1);
    float lx = fmaxf(x1, G[5]);
    float rx = fminf(x2, G[7]);
    float uy = fmaxf(y1, G[6]);
    float dy = fminf(y2, G[8]);
    float inter = (rx - lx) * (dy - uy);
    bool valid = (rx >= lx) && (dy >= uy);
    return valid ? inter / (parea + G[9] - inter) : 0.0f;
}

__global__ __launch_bounds__(128) void yolo_v1_loss_main(
    const float* __restrict__ bbf, const float* __restrict__ gtf,
    float* __restrict__ ws) {
    __shared__ char lds[WPB][2][TB];  // 61440 B

    const int tid = threadIdx.x;
    const int lane = tid & 63;
    const int w = tid >> 6;
    const int gw = blockIdx.x * WPB + w;  // 0..NW-1
    const int t0 = gw * TPW;              // 4 consecutive tiles per wave

    const char* bb = (const char*)bbf;
    const char* gt = (const char*)gtf;
    char* buf0 = lds[w][0];
    char* buf1 = lds[w][1];

    float acc[6] = {0.f, 0.f, 0.f, 0.f, 0.f, 0.f};

    stage_tile(bb, gt, buf0, t0, lane);  // prologue

#pragma unroll
    for (int k = 0; k < TPW; ++k) {
        char* cur = (k & 1) ? buf1 : buf0;
        char* nxt = (k & 1) ? buf0 : buf1;

        if (k + 1 < TPW) {
            // WAR on nxt is safe: its readers (iter k-1) completed >=1 full
            // HBM latency ago; gll data lands ~500+ cy from now.
            stage_tile(bb, gt, nxt, t0 + k + 1, lane);
            __builtin_amdgcn_sched_barrier(0);  // gll must precede the wait
            asm volatile("s_waitcnt vmcnt(15)" ::: "memory");  // tile k landed
        } else {
            __builtin_amdgcn_sched_barrier(0);
            asm volatile("s_waitcnt vmcnt(0)" ::: "memory");  // last tile
        }
        __builtin_amdgcn_sched_barrier(0);  // ds_reads must not hoist (rule 18)

        // ---- LDS gather: lane l owns cell l (120-B stride) ----
        float vb[CH], vg[CH];
        const float2* pb2 = (const float2*)(cur + lane * 120);
        const float2* pg2 = (const float2*)(cur + AB + lane * 120);
#pragma unroll
        for (int i = 0; i < 15; ++i) {
            *(float2*)(vb + 2 * i) = pb2[i];
            *(float2*)(vg + 2 * i) = pg2[i];
        }

        // ---- per-cell math ----
        int cell = (t0 + k) * TCELLS + lane;
        int rem = cell % 49;
        int gy = rem / 7;
        int gx = rem - gy * 7;
        float fx = (float)gx, fy = (float)gy;

        const float* B = vb;
        const float* G = vg;

        float iou1 = iou_one(B, G, fx, fy);
        float iou2 = iou_one(B + 5, G, fx, fy);
        bool r1 = iou1 > iou2;
        const float* P = r1 ? B : (B + 5);   // responsible box
        const float* Nb = r1 ? (B + 5) : B;  // other box
        float iou = r1 ? iou1 : iou2;

        float fm = (rintf(G[4]) != 0.0f) ? 1.0f : 0.0f;
        float noobj = 0.5f * (B[4] * B[4] + B[9] * B[9]);

        float dx = P[0] - G[0];
        float dyv = P[1] - G[1];
        float dw = sqrtf(P[2]) - sqrtf(G[2]);
        float dh = sqrtf(P[3]) - sqrtf(G[3]);
        float coord = 5.0f * (dx * dx + dyv * dyv + dw * dw + dh * dh);

        float dc = P[4] - iou;
        float conf = dc * dc + 0.5f * Nb[4] * Nb[4];

        float cls = 0.f;
#pragma unroll
        for (int kk = 0; kk < 20; ++kk) {
            float d = G[10 + kk] - B[10 + kk];
            cls += d * d;
        }

        float ifm = 1.0f - fm;
        acc[0] += fm * (coord + conf + cls) + ifm * noobj;
        acc[1] += fm * coord;
        acc[2] += fm * conf + ifm * noobj;
        acc[3] += fm * cls;
        acc[4] += fm * iou;
        acc[5] += fm;
    }

    // ---- wave reduce (64-wide), partials straight to workspace ----
#pragma unroll
    for (int off = 32; off > 0; off >>= 1) {
#pragma unroll
        for (int j = 0; j < 6; ++j) acc[j] += __shfl_down(acc[j], off);
    }
    if (lane == 0) {
#pragma unroll
        for (int j = 0; j < 6; ++j) ws[j * NW + gw] = acc[j];
    }
}

// 768 threads = 12 waves; 128 threads (2 waves) per output j.
__global__ __launch_bounds__(768) void yolo_v1_loss_reduce(
    const float* __restrict__ ws, float* __restrict__ out) {
    __shared__ float sp[12];
    const int tid = threadIdx.x;
    const int j = tid >> 7;  // 0..5
    const int sub = tid & 127;
    float s = 0.f;
    for (int i = sub; i < NW; i += 128) s += ws[j * NW + i];
#pragma unroll
    for (int off = 32; off > 0; off >>= 1) s += __shfl_down(s, off);
    const int wave = tid >> 6;
    if ((tid & 63) == 0) sp[wave] = s;
    __syncthreads();
    if (tid < 6) out[tid] = sp[2 * tid] + sp[2 * tid + 1];
}

extern "C" void kernel_launch(void* const* d_in, const int* in_sizes, int n_in,
                              void* d_out, int out_size, void* d_ws,
                              size_t ws_size, hipStream_t stream) {
    const float* bb = (const float*)d_in[0];
    const float* gt = (const float*)d_in[1];
    float* out = (float*)d_out;
    float* ws = (float*)d_ws;
    yolo_v1_loss_main<<<NBLOCKS, 128, 0, stream>>>(bb, gt, ws);
    yolo_v1_loss_reduce<<<1, 768, 0, stream>>>(ws, out);
}